// Round 6
// baseline (633.199 us; speedup 1.0000x reference)
//
#include <hip/hip_runtime.h>

#define B_ 256
#define D_ 784
#define V_ 128
#define S_ 2
#define BD (B_ * D_)
#define RPB 4            // batch rows per fused block
#define NBLK (B_ / RPB)  // 64 blocks
#define TPB 832          // 13 waves; threads 0..783 own one d column

__device__ __forceinline__ void get_params(const int* kiter, float& ss, float& bal) {
    int k = kiter[0] % 10;
    ss  = (k == 0) ? 0.5f : 0.1f;
    bal = (k == 0) ? 0.9f : 0.6f;
}

__device__ __forceinline__ double wave_red(double v) {
#pragma unroll
    for (int o = 32; o > 0; o >>= 1) v += __shfl_down(v, o, 64);
    return v;
}

// ---------------------------------------------------------------------------
// wsym_xf_k: Wsym = 0.5*(W + W^T) via LDS-tiled transpose (both sides
// coalesced); also pre-converts x -> float (xf).
// ---------------------------------------------------------------------------
__global__ __launch_bounds__(256) void wsym_xf_k(
    const float* __restrict__ W, const int* __restrict__ x,
    float* __restrict__ wsym, float* __restrict__ xf)
{
    __shared__ float T[64][65];
    const int tid = threadIdx.x;
    const int i0 = blockIdx.x * 64, j0 = blockIdx.y * 64;

#pragma unroll
    for (int m = 0; m < 16; ++m) {
        int idx = m * 256 + tid;
        int r = idx >> 6, c = idx & 63;
        if (j0 + r < D_ && i0 + c < D_)
            T[r][c] = W[(j0 + r) * D_ + i0 + c];
    }
    __syncthreads();
#pragma unroll
    for (int m = 0; m < 16; ++m) {
        int idx = m * 256 + tid;
        int r = idx >> 6, c = idx & 63;
        if (i0 + r < D_ && j0 + c < D_)
            wsym[(i0 + r) * D_ + j0 + c] =
                0.5f * (W[(i0 + r) * D_ + j0 + c] + T[c][r]);
    }
    // x -> float, strided over the 13x13 grid
    const int bid = blockIdx.y * 13 + blockIdx.x;
    for (int g = bid * 256 + tid; g < BD; g += 169 * 256)
        xf[g] = (float)x[g];
}

// ---------------------------------------------------------------------------
// fwd_fused: GEMV-style GEMM (4 rows/block, A wave-uniform -> s_load;
// Wsym column load coalesced) + windowed categorical + lse + combined
// q_f[b] = lp_forward + 0.5*E(xf) row-reduction.
// Window: lg(v) = a1*dv - c2*dv^2 concave, vertex v0 = xf + a1*ss; gumbel
// range [-2.626,13.816] => deficit > 16.45 can't win argmax; lse tail at
// drop>30 < 1.2e-11 rel. Span <= 12 values <= 4 quads.
// ---------------------------------------------------------------------------
__global__ __launch_bounds__(TPB) void fwd_fused(
    const int* __restrict__ xin, const float* __restrict__ xfA,
    const float* __restrict__ wsym, const float* __restrict__ bvec,
    const float* __restrict__ gumbel, const int* __restrict__ kiter, int s,
    int* __restrict__ x_delta, float* __restrict__ xdf,
    double* __restrict__ qf)
{
    const int tid = threadIdx.x, d = tid;
    const int r0 = blockIdx.x * RPB;
    float ss, bal; get_params(kiter, ss, bal);
    const float c2 = 0.5f / ss;

    double q[RPB] = {};

    if (d < D_) {
        // ---- GEMM: g[r] = sum_k xfA[r0+r][k] * Wsym[k][d] ----
        const int a0 = (r0 + 0) * D_, a1r = (r0 + 1) * D_;
        const int a2 = (r0 + 2) * D_, a3 = (r0 + 3) * D_;
        float acc0 = 0.f, acc1 = 0.f, acc2 = 0.f, acc3 = 0.f;
#pragma unroll 4
        for (int k = 0; k < D_; ++k) {
            const float wv = wsym[k * D_ + d];      // coalesced vector load
            acc0 = fmaf(xfA[a0 + k], wv, acc0);     // uniform -> s_load
            acc1 = fmaf(xfA[a1r + k], wv, acc1);
            acc2 = fmaf(xfA[a2 + k], wv, acc2);
            acc3 = fmaf(xfA[a3 + k], wv, acc3);
        }
        const float accs[RPB] = {acc0, acc1, acc2, acc3};
        const float bvd = bvec[d];

#pragma unroll
        for (int r = 0; r < RPB; ++r) {
            const int b = r0 + r, bd = b * D_ + d;
            const int xi = xin[bd];
            const float xfv = (float)xi;
            const float gv = accs[r] + bvd;

            const float a1 = bal * gv;
            const float v0 = xfv + a1 * ss;
            int vm = (int)rintf(v0); vm = min(127, max(0, vm));
            const float dmv = v0 - (float)vm;
            const float Reff = sqrtf(30.0f / c2 + dmv * dmv);
            int lo = max(0, (int)ceilf(v0 - Reff));
            int hi = min(127, (int)floorf(v0 + Reff));
            lo = min(lo, vm); hi = max(hi, vm);

            const float dvm = (float)vm - xfv;
            const float mL = dvm * fmaf(-c2, dvm, a1);   // exact max (concavity)

            const float4* __restrict__ gq =
                (const float4*)(gumbel + (((size_t)s * B_ + b) * D_ + d) * V_);
            const int q0 = lo >> 2, qh = hi >> 2;        // qh - q0 <= 3
            float4 quad[4];
#pragma unroll
            for (int j = 0; j < 4; ++j) quad[j] = gq[min(q0 + j, qh)];

            float best = -1e30f; int imax = vm;
            float sum0 = 0.f, sum1 = 0.f;
#pragma unroll
            for (int j = 0; j < 4; ++j) {
                const int qi = q0 + j;
                const bool qok = qi <= qh;
                const float qs[4] = {quad[j].x, quad[j].y, quad[j].z, quad[j].w};
#pragma unroll
                for (int c = 0; c < 4; ++c) {
                    int v = 4 * qi + c;
                    bool ok = qok && v >= lo && v <= hi;
                    float dv = (float)v - xfv;
                    float lg = dv * fmaf(-c2, dv, a1);
                    float y = ok ? (lg + qs[c]) : -1e30f;
                    if (y > best) { best = y; imax = v; }  // ascending, strict >
                    float e = expf(lg - mL);
                    if (c & 1) sum1 += ok ? e : 0.f; else sum0 += ok ? e : 0.f;
                }
            }
            float lse = mL + logf(sum0 + sum1);
            float dvc = (float)imax - xfv;
            float lch = dvc * fmaf(-c2, dvc, a1);
            // q = lp + 0.5*E-term  (la = q_d - q_f)
            q[r] = (double)(lch - lse)
                 + 0.5 * (double)xfv * ((double)gv + (double)bvd);
            x_delta[bd] = imax;
            xdf[bd] = (float)imax;
        }
    }

    __shared__ double wred[13][RPB];
    const int lane = tid & 63, wv_ = tid >> 6;
#pragma unroll
    for (int r = 0; r < RPB; ++r) {
        double t = wave_red(q[r]);
        if (lane == 0) wred[wv_][r] = t;
    }
    __syncthreads();
    if (tid < RPB) {
        double sm = 0;
        for (int w = 0; w < 13; ++w) sm += wred[w][tid];
        qf[r0 + tid] = sm;
    }
}

// ---------------------------------------------------------------------------
// rev_fused: GEMM on x_delta + windowed lse (gather at x_cur) + combined
// q_d row-reduction + MH accept + x update + final output.
// ---------------------------------------------------------------------------
__global__ __launch_bounds__(TPB) void rev_fused(
    const int* __restrict__ xin, const float* __restrict__ xdfA,
    const int* __restrict__ x_delta,
    const float* __restrict__ wsym, const float* __restrict__ bvec,
    const float* __restrict__ u, const int* __restrict__ kiter,
    int s, int last, const double* __restrict__ qf,
    int* __restrict__ x_cur, float* __restrict__ xf_out,
    float* __restrict__ out)
{
    const int tid = threadIdx.x, d = tid;
    const int r0 = blockIdx.x * RPB;
    float ss, bal; get_params(kiter, ss, bal);
    const float c2 = 0.5f / ss;

    double q[RPB] = {};

    if (d < D_) {
        const int a0 = (r0 + 0) * D_, a1r = (r0 + 1) * D_;
        const int a2 = (r0 + 2) * D_, a3 = (r0 + 3) * D_;
        float acc0 = 0.f, acc1 = 0.f, acc2 = 0.f, acc3 = 0.f;
#pragma unroll 4
        for (int k = 0; k < D_; ++k) {
            const float wv = wsym[k * D_ + d];
            acc0 = fmaf(xdfA[a0 + k], wv, acc0);
            acc1 = fmaf(xdfA[a1r + k], wv, acc1);
            acc2 = fmaf(xdfA[a2 + k], wv, acc2);
            acc3 = fmaf(xdfA[a3 + k], wv, acc3);
        }
        const float accs[RPB] = {acc0, acc1, acc2, acc3};
        const float bvd = bvec[d];

#pragma unroll
        for (int r = 0; r < RPB; ++r) {
            const int b = r0 + r, bd = b * D_ + d;
            const int xi = xin[bd];
            const int xd = x_delta[bd];
            const float xdv = (float)xd;
            const float gv = accs[r] + bvd;

            const float a1 = bal * gv;
            const float v0 = xdv + a1 * ss;
            int vm = (int)rintf(v0); vm = min(127, max(0, vm));
            const float dmv = v0 - (float)vm;
            const float Reff = sqrtf(30.0f / c2 + dmv * dmv);
            int lo = max(0, (int)ceilf(v0 - Reff));
            int hi = min(127, (int)floorf(v0 + Reff));
            lo = min(lo, vm); hi = max(hi, vm);

            const float dvm = (float)vm - xdv;
            const float mL = dvm * fmaf(-c2, dvm, a1);
            float sum0 = 0.f, sum1 = 0.f;
#pragma unroll
            for (int j = 0; j < 16; ++j) {       // span <= 12, predicated
                int v = lo + j;
                bool ok = v <= hi;
                float dv = (float)v - xdv;
                float lg = dv * fmaf(-c2, dv, a1);
                float e = expf(lg - mL);
                if (j & 1) sum1 += ok ? e : 0.f; else sum0 += ok ? e : 0.f;
            }
            float lse = mL + logf(sum0 + sum1);
            float dvc = (float)xi - xdv;          // logp_d gathered at x_cur
            float lch = dvc * fmaf(-c2, dvc, a1);
            q[r] = (double)(lch - lse)
                 + 0.5 * (double)xdv * ((double)gv + (double)bvd);
        }
    }

    __shared__ double wred[13][RPB];
    __shared__ int acc_s[RPB];
    __shared__ float la_s[RPB];
    const int lane = tid & 63, wv_ = tid >> 6;
#pragma unroll
    for (int r = 0; r < RPB; ++r) {
        double t = wave_red(q[r]);
        if (lane == 0) wred[wv_][r] = t;
    }
    __syncthreads();
    if (tid < RPB) {
        double sm = 0;
        for (int w = 0; w < 13; ++w) sm += wred[w][tid];
        double la = sm - qf[r0 + tid];
        acc_s[tid] = (exp(la) > (double)u[s * B_ + r0 + tid]) ? 1 : 0;
        la_s[tid] = (float)la;
    }
    __syncthreads();

    if (d < D_) {
#pragma unroll
        for (int r = 0; r < RPB; ++r) {
            const int bd = (r0 + r) * D_ + d;
            int xn = acc_s[r] ? x_delta[bd] : xin[bd];
            x_cur[bd] = xn;
            xf_out[bd] = (float)xn;
            if (last) out[bd] = (float)xn;
        }
    }
    if (last && tid < RPB) out[BD + r0 + tid] = la_s[tid];
}

// ---------------------------------------------------------------------------
extern "C" void kernel_launch(void* const* d_in, const int* in_sizes, int n_in,
                              void* d_out, int out_size, void* d_ws, size_t ws_size,
                              hipStream_t stream)
{
    const int*   x     = (const int*)d_in[0];
    const float* W     = (const float*)d_in[1];
    const float* bv    = (const float*)d_in[2];
    const float* gum   = (const float*)d_in[3];
    const float* u     = (const float*)d_in[4];
    const int*   kiter = (const int*)d_in[5];
    float* out = (float*)d_out;

    char* w = (char*)d_ws;
    size_t off = 0;
    auto carve = [&](size_t bytes) { void* p = w + off; off += (bytes + 511) & ~511ull; return p; };
    float*  wsym    = (float*) carve((size_t)D_ * D_ * 4);
    int*    x_cur   = (int*)   carve((size_t)BD * 4);
    int*    x_delta = (int*)   carve((size_t)BD * 4);
    float*  xf      = (float*) carve((size_t)BD * 4);   // float(x_cur)
    float*  xdf     = (float*) carve((size_t)BD * 4);   // float(x_delta)
    double* qf      = (double*)carve(B_ * 8);
    (void)ws_size; (void)in_sizes; (void)n_in; (void)out_size;

    wsym_xf_k<<<dim3(13, 13), 256, 0, stream>>>(W, x, wsym, xf);

    for (int s = 0; s < S_; ++s) {
        const int* xin = (s == 0) ? x : x_cur;
        fwd_fused<<<NBLK, TPB, 0, stream>>>(xin, xf, wsym, bv, gum, kiter, s,
                                            x_delta, xdf, qf);
        rev_fused<<<NBLK, TPB, 0, stream>>>(xin, xdf, x_delta, wsym, bv, u, kiter,
                                            s, (s == S_ - 1) ? 1 : 0, qf,
                                            x_cur, xf, out);
    }
}